// Round 2
// baseline (843.531 us; speedup 1.0000x reference)
//
#include <hip/hip_runtime.h>

#define NN 50000
#define NM 50000
#define F  128
#define NBUK 782      // ceil(50000/64)
#define NCHUNK 49     // ceil(50000/1024)

// ---------------- GEMM: x = X @ W  ([NN,128] @ [128,128], f32 vector ALU) --------
__global__ __launch_bounds__(256) void gemm_k(const float* __restrict__ X,
                                              const float* __restrict__ W,
                                              float* __restrict__ xo) {
    __shared__ float sW[128 * 128];   // 64 KB
    __shared__ float sX[16 * 128];    // 8 KB
    int t = threadIdx.x;

    const float4* W4 = (const float4*)W;
    float4* sW4 = (float4*)sW;
#pragma unroll
    for (int i = 0; i < 16; ++i) sW4[i * 256 + t] = W4[i * 256 + t];

    const float4* X4 = (const float4*)(X + (size_t)blockIdx.x * 16 * 128);
    float4* sX4 = (float4*)sX;
    sX4[t]       = X4[t];
    sX4[t + 256] = X4[t + 256];
    __syncthreads();

    int l = t & 63, w = t >> 6;           // lane, wave (4 waves, 4 rows each)
    float acc[4][2] = {};
#pragma unroll 4
    for (int k = 0; k < 128; ++k) {
        float w0 = sW[k * 128 + l];
        float w1 = sW[k * 128 + 64 + l];
#pragma unroll
        for (int r = 0; r < 4; ++r) {
            float xv = sX[(w * 4 + r) * 128 + k];
            acc[r][0] = fmaf(xv, w0, acc[r][0]);
            acc[r][1] = fmaf(xv, w1, acc[r][1]);
        }
    }
    int row0 = blockIdx.x * 16 + w * 4;
#pragma unroll
    for (int r = 0; r < 4; ++r) {
        xo[(size_t)(row0 + r) * 128 + l]      = acc[r][0];
        xo[(size_t)(row0 + r) * 128 + 64 + l] = acc[r][1];
    }
}

// ---------------- degree counting (both directions in one pass) ------------------
__global__ void count_k(const int* __restrict__ nodes, const int* __restrict__ hedges,
                        int* __restrict__ cnt_v, int* __restrict__ cnt_h, int E) {
    int e = blockIdx.x * 256 + threadIdx.x;
    if (e < E) {
        atomicAdd(&cnt_v[nodes[e]], 1);
        atomicAdd(&cnt_h[hedges[e]], 1);
    }
}

// ---------------- parallel scan: A (per-chunk), B (chunk totals), C (apply) ------
__global__ __launch_bounds__(1024) void scanA_k(const int* __restrict__ cnt_h, int* __restrict__ off_h,
                                                const int* __restrict__ cnt_v, int* __restrict__ off_v,
                                                int* __restrict__ tot) {
    __shared__ int s16[16];
    int arr = blockIdx.x / NCHUNK;
    int c   = blockIdx.x % NCHUNK;
    const int* cnt = arr ? cnt_v : cnt_h;
    int* off = arr ? off_v : off_h;
    int n = arr ? NN : NM;
    int t = threadIdx.x, lane = t & 63, wid = t >> 6;
    int i = c * 1024 + t;
    int v = (i < n) ? cnt[i] : 0;
    int incl = v;
#pragma unroll
    for (int s = 1; s < 64; s <<= 1) {
        int u = __shfl_up(incl, s, 64);
        if (lane >= s) incl += u;
    }
    if (lane == 63) s16[wid] = incl;
    __syncthreads();
    if (t < 16) {
        int wv = s16[t];
        int wincl = wv;
#pragma unroll
        for (int s = 1; s < 16; s <<= 1) {
            int u = __shfl_up(wincl, s, 64);
            if (t >= s) wincl += u;
        }
        s16[t] = wincl - wv;              // exclusive wave offset
    }
    __syncthreads();
    int full = incl + s16[wid];
    if (i < n) off[i + 1] = full;         // chunk-local inclusive scan
    if (t == 1023) tot[blockIdx.x] = full;
}

__global__ __launch_bounds__(128) void scanB_k(const int* __restrict__ tot, int* __restrict__ base) {
    int arr = threadIdx.x >> 6, lane = threadIdx.x & 63;
    int v = (lane < NCHUNK) ? tot[arr * NCHUNK + lane] : 0;
    int incl = v;
#pragma unroll
    for (int s = 1; s < 64; s <<= 1) {
        int u = __shfl_up(incl, s, 64);
        if (lane >= s) incl += u;
    }
    if (lane < NCHUNK) base[arr * NCHUNK + lane] = incl - v;  // exclusive
}

__global__ __launch_bounds__(1024) void scanC_k(int* __restrict__ off_h, int* __restrict__ off_v,
                                                const int* __restrict__ base,
                                                int* __restrict__ bcur_h, int* __restrict__ bcur_v) {
    int arr = blockIdx.x / NCHUNK;
    int c   = blockIdx.x % NCHUNK;
    int* off  = arr ? off_v  : off_h;
    int* bcur = arr ? bcur_v : bcur_h;
    int n = arr ? NN : NM;
    int i = c * 1024 + threadIdx.x;
    if (i < n) {
        int val = off[i + 1] + base[arr * NCHUNK + c];
        off[i + 1] = val;
        if (((i + 1) & 63) == 0) bcur[(i + 1) >> 6] = val;  // bucket start cursor
    }
    if (c == 0 && threadIdx.x == 0) { off[0] = 0; bcur[0] = 0; }
}

// ---------------- pass 1: bucket-append packed pairs (sequential streams) --------
__global__ __launch_bounds__(256) void binfill_k(const int* __restrict__ nodes, const int* __restrict__ hedges,
                                                 int* __restrict__ bcur_h, int* __restrict__ bcur_v,
                                                 int* __restrict__ pair_h, int* __restrict__ pair_v, int E) {
    int e = blockIdx.x * 256 + threadIdx.x;
    if (e < E) {
        int v = nodes[e], h = hedges[e];
        int ph = atomicAdd(&bcur_h[h >> 6], 1);
        pair_h[ph] = ((h & 63) << 16) | v;     // ids < 65536, fit 16 bits
        int pv = atomicAdd(&bcur_v[v >> 6], 1);
        pair_v[pv] = ((v & 63) << 16) | h;
    }
}

// ---------------- pass 2: per-bucket scatter with LDS-private cursors ------------
__global__ __launch_bounds__(256) void scatter_k(const int* __restrict__ pair_h, const int* __restrict__ off_h, int* __restrict__ adj_h,
                                                 const int* __restrict__ pair_v, const int* __restrict__ off_v, int* __restrict__ adj_v) {
    __shared__ int lcur[64];
    int arr = blockIdx.x / NBUK;
    int b   = blockIdx.x % NBUK;
    const int* pair = arr ? pair_v : pair_h;
    const int* off  = arr ? off_v  : off_h;
    int* adj        = arr ? adj_v  : adj_h;
    int n = arr ? NN : NM;
    int d0 = b * 64;
    int dc = min(64, n - d0);
    int t = threadIdx.x;
    if (t < dc) lcur[t] = off[d0 + t];
    __syncthreads();
    int p0 = off[d0], p1 = off[d0 + dc];
    for (int p = p0 + t; p < p1; p += 256) {
        int pr = pair[p];
        int slot = atomicAdd(&lcur[pr >> 16], 1);
        adj[slot] = pr & 0xFFFF;
    }
}

// ---------------- pass A: m[h] = B_inv[h] * sum_{v in h} x[v] --------------------
__global__ __launch_bounds__(256) void agg_a_k(const float* __restrict__ x,
                                               const int* __restrict__ adj,
                                               const int* __restrict__ off,
                                               float* __restrict__ m) {
    int h = blockIdx.x * 4 + (threadIdx.x >> 6);
    int l = threadIdx.x & 63;
    int s = off[h], e = off[h + 1];
    float ax = 0.f, ay = 0.f;
#pragma unroll 4
    for (int i = s; i < e; ++i) {
        int n = adj[i];
        float2 v = *(const float2*)(x + (size_t)n * 128 + 2 * l);
        ax += v.x; ay += v.y;
    }
    float inv = (e > s) ? 1.0f / (float)(e - s) : 0.0f;
    ((float2*)m)[(size_t)h * 64 + l] = make_float2(ax * inv, ay * inv);
}

// ---------------- pass B: out[v] = softmax(D_inv[v]*sum m[h] + b) ----------------
__global__ __launch_bounds__(256) void agg_b_k(const float* __restrict__ m,
                                               const int* __restrict__ adj,
                                               const int* __restrict__ off,
                                               const float* __restrict__ bias,
                                               float* __restrict__ out) {
    int v = blockIdx.x * 4 + (threadIdx.x >> 6);
    int l = threadIdx.x & 63;
    int s = off[v], e = off[v + 1];
    float ax = 0.f, ay = 0.f;
#pragma unroll 4
    for (int i = s; i < e; ++i) {
        int h = adj[i];
        float2 t = *(const float2*)(m + (size_t)h * 128 + 2 * l);
        ax += t.x; ay += t.y;
    }
    float inv = (e > s) ? 1.0f / (float)(e - s) : 0.0f;
    float2 bb = ((const float2*)bias)[l];
    float v0 = ax * inv + bb.x;
    float v1 = ay * inv + bb.y;

    float mx = fmaxf(v0, v1);
#pragma unroll
    for (int s2 = 32; s2 >= 1; s2 >>= 1) mx = fmaxf(mx, __shfl_xor(mx, s2, 64));
    float e0 = __expf(v0 - mx), e1 = __expf(v1 - mx);
    float sm = e0 + e1;
#pragma unroll
    for (int s2 = 32; s2 >= 1; s2 >>= 1) sm += __shfl_xor(sm, s2, 64);
    float r = 1.0f / sm;
    ((float2*)out)[(size_t)v * 64 + l] = make_float2(e0 * r, e1 * r);
}

// ---------------- launcher -------------------------------------------------------
extern "C" void kernel_launch(void* const* d_in, const int* in_sizes, int n_in,
                              void* d_out, int out_size, void* d_ws, size_t ws_size,
                              hipStream_t stream) {
    const float* X  = (const float*)d_in[0];
    const int*   ei = (const int*)d_in[1];
    const float* W  = (const float*)d_in[2];
    const float* b  = (const float*)d_in[3];
    float* out = (float*)d_out;

    int E = in_sizes[1] / 2;
    const int* nodes  = ei;
    const int* hedges = ei + E;

    // workspace layout (~65 MB)
    float* x     = (float*)d_ws;                     // NN*F floats
    float* m     = x + (size_t)NN * F;               // NM*F floats
    int*   pair_h = (int*)m;                         // E ints (aliased in m: consumed before m is written)
    int*   pair_v = pair_h + E;                      // E ints (2E*4B = 12.8MB <= 25.6MB)
    int*   adj_h = (int*)(m + (size_t)NM * F);       // E
    int*   adj_v = adj_h + E;                        // E
    int*   cnt_h = adj_v + E;                        // NM
    int*   cnt_v = cnt_h + NM;                       // NN
    int*   off_h = cnt_v + NN;                       // NM+1
    int*   off_v = off_h + (NM + 1);                 // NN+1
    int*   bcur_h = off_v + (NN + 1);                // NBUK
    int*   bcur_v = bcur_h + NBUK;                   // NBUK
    int*   tot   = bcur_v + NBUK;                    // 2*NCHUNK
    int*   base  = tot + 2 * NCHUNK;                 // 2*NCHUNK

    hipMemsetAsync(cnt_h, 0, sizeof(int) * (size_t)(NM + NN), stream);

    gemm_k<<<NN / 16, 256, 0, stream>>>(X, W, x);
    count_k<<<(E + 255) / 256, 256, 0, stream>>>(nodes, hedges, cnt_v, cnt_h, E);
    scanA_k<<<2 * NCHUNK, 1024, 0, stream>>>(cnt_h, off_h, cnt_v, off_v, tot);
    scanB_k<<<1, 128, 0, stream>>>(tot, base);
    scanC_k<<<2 * NCHUNK, 1024, 0, stream>>>(off_h, off_v, base, bcur_h, bcur_v);
    binfill_k<<<(E + 255) / 256, 256, 0, stream>>>(nodes, hedges, bcur_h, bcur_v, pair_h, pair_v, E);
    scatter_k<<<2 * NBUK, 256, 0, stream>>>(pair_h, off_h, adj_h, pair_v, off_v, adj_v);
    agg_a_k<<<NM / 4, 256, 0, stream>>>(x, adj_h, off_h, m);
    agg_b_k<<<NN / 4, 256, 0, stream>>>(m, adj_v, off_v, b, out);
}

// Round 3
// 371.630 us; speedup vs baseline: 2.2698x; 2.2698x over previous
//
#include <hip/hip_runtime.h>

#define NN 50000
#define NM 50000
#define F  128
#define NBUK 782      // ceil(50000/64) buckets of 64 dest ids
#define CHSZ 8192     // edges per sort chunk

// ---------------- block-scan helpers ---------------------------------------------
__device__ __forceinline__ int wscan64(int v, int lane) {
    int x = v;
#pragma unroll
    for (int s = 1; s < 64; s <<= 1) {
        int u = __shfl_up(x, s, 64);
        if (lane >= s) x += u;
    }
    return x;   // inclusive
}

// exclusive scan over 256 threads' values; returns exclusive, *tot = total.
// Uses s5[5] shared; internally syncs; safe to call in a uniform loop.
__device__ __forceinline__ int bscan256(int v, int* s5, int* tot) {
    int t = threadIdx.x, lane = t & 63, wid = t >> 6;
    int incl = wscan64(v, lane);
    if (lane == 63) s5[wid] = incl;
    __syncthreads();
    if (t == 0) {
        int a = 0;
#pragma unroll
        for (int j = 0; j < 4; ++j) { int x = s5[j]; s5[j] = a; a += x; }
        s5[4] = a;
    }
    __syncthreads();
    int ex = incl - v + s5[wid];
    *tot = s5[4];
    __syncthreads();   // protect s5 for next invocation
    return ex;
}

// ---------------- GEMM: x = X @ W  ([NN,128] @ [128,128], f32 vector ALU) --------
__global__ __launch_bounds__(256) void gemm_k(const float* __restrict__ X,
                                              const float* __restrict__ W,
                                              float* __restrict__ xo) {
    __shared__ float sW[128 * 128];
    __shared__ float sX[16 * 128];
    int t = threadIdx.x;

    const float4* W4 = (const float4*)W;
    float4* sW4 = (float4*)sW;
#pragma unroll
    for (int i = 0; i < 16; ++i) sW4[i * 256 + t] = W4[i * 256 + t];

    const float4* X4 = (const float4*)(X + (size_t)blockIdx.x * 16 * 128);
    float4* sX4 = (float4*)sX;
    sX4[t]       = X4[t];
    sX4[t + 256] = X4[t + 256];
    __syncthreads();

    int l = t & 63, w = t >> 6;
    float acc[4][2] = {};
#pragma unroll 4
    for (int k = 0; k < 128; ++k) {
        float w0 = sW[k * 128 + l];
        float w1 = sW[k * 128 + 64 + l];
#pragma unroll
        for (int r = 0; r < 4; ++r) {
            float xv = sX[(w * 4 + r) * 128 + k];
            acc[r][0] = fmaf(xv, w0, acc[r][0]);
            acc[r][1] = fmaf(xv, w1, acc[r][1]);
        }
    }
    int row0 = blockIdx.x * 16 + w * 4;
#pragma unroll
    for (int r = 0; r < 4; ++r) {
        xo[(size_t)(row0 + r) * 128 + l]      = acc[r][0];
        xo[(size_t)(row0 + r) * 128 + 64 + l] = acc[r][1];
    }
}

// ---------------- 1: per-chunk LDS counting sort ---------------------------------
// dir0: key=hedge, payload=node (-> adj_h). dir1: key=node, payload=hedge.
__global__ __launch_bounds__(256) void chunksort_k(const int* __restrict__ nodes,
                                                   const int* __restrict__ hedges,
                                                   int* __restrict__ gchunk0, int* __restrict__ gchunk1,
                                                   int* __restrict__ ghist, int* __restrict__ gstart,
                                                   int E, int NCH) {
    __shared__ int hist[NBUK];
    __shared__ int cursor[NBUK];
    __shared__ int pairs[CHSZ];
    __shared__ int s5[5];
    int dir = blockIdx.x / NCH;
    int c   = blockIdx.x % NCH;
    const int* key = dir ? nodes  : hedges;
    const int* pay = dir ? hedges : nodes;
    int* gchunk    = dir ? gchunk1 : gchunk0;
    int t = threadIdx.x;
    int e0 = c * CHSZ, e1 = min(E, e0 + CHSZ);

    for (int i = t; i < NBUK; i += 256) hist[i] = 0;
    __syncthreads();
    for (int e = e0 + t; e < e1; e += 256) atomicAdd(&hist[key[e] >> 6], 1);
    __syncthreads();

    // exclusive scan hist -> cursor (782 values, 4 tiles with carry)
    int carry = 0;
    for (int base = 0; base < NBUK; base += 256) {
        int i = base + t;
        int v = (i < NBUK) ? hist[i] : 0;
        int tot;
        int ex = bscan256(v, s5, &tot);
        if (i < NBUK) cursor[i] = ex + carry;
        carry += tot;
    }
    __syncthreads();

    // publish per-(bucket,chunk) len + local start
    for (int b = t; b < NBUK; b += 256) {
        size_t idx = ((size_t)dir * NBUK + b) * NCH + c;
        ghist[idx]  = hist[b];
        gstart[idx] = cursor[b];
    }
    __syncthreads();

    // counting-sort chunk into LDS
    for (int e = e0 + t; e < e1; e += 256) {
        int k = key[e];
        int pos = atomicAdd(&cursor[k >> 6], 1);
        pairs[pos] = ((k & 63) << 16) | pay[e];
    }
    __syncthreads();

    int n = e1 - e0;
    for (int i = t; i < n; i += 256) gchunk[(size_t)c * CHSZ + i] = pairs[i];
}

// ---------------- 2: bucket totals -> global bucket starts -----------------------
__global__ __launch_bounds__(1024) void bucketbase_k(const int* __restrict__ ghist,
                                                     int* __restrict__ bstart,
                                                     int* __restrict__ off0, int* __restrict__ off1,
                                                     int E, int NCH) {
    __shared__ int s16[17];
    int dir = blockIdx.x;
    int t = threadIdx.x, lane = t & 63, wid = t >> 6;
    int v = 0;
    if (t < NBUK) {
        const int* row = ghist + ((size_t)dir * NBUK + t) * NCH;
        int s = 0;
        for (int c = 0; c < NCH; ++c) s += row[c];
        v = s;
    }
    int incl = wscan64(v, lane);
    if (lane == 63) s16[wid] = incl;
    __syncthreads();
    if (t < 16) {
        int x = s16[t], y = x;
#pragma unroll
        for (int s = 1; s < 16; s <<= 1) {
            int u = __shfl_up(y, s, 64);
            if (t >= s) y += u;
        }
        s16[t] = y - x;
    }
    __syncthreads();
    int ex = incl - v + s16[wid];
    if (t < NBUK) bstart[dir * NBUK + t] = ex;
    if (t == 0) (dir ? off1 : off0)[50000] = E;
}

// ---------------- 3: per-bucket merge + fine sort + scatter (block-exclusive) ----
__global__ __launch_bounds__(256) void merge_scatter_k(const int* __restrict__ gchunk0, const int* __restrict__ gchunk1,
                                                       const int* __restrict__ ghist, const int* __restrict__ gstart,
                                                       const int* __restrict__ bstart,
                                                       int* __restrict__ adj0, int* __restrict__ adj1,
                                                       int* __restrict__ off0, int* __restrict__ off1,
                                                       int NCH) {
    __shared__ int slen_src[256];          // packed? keep separate:
    __shared__ int ssrc[256];
    __shared__ int sdst[257];
    __shared__ int s5[5];
    __shared__ int pairsS[CHSZ];
    __shared__ int fcnt[64], foff[64], fcur[64];
    (void)slen_src;

    int dir = blockIdx.x / NBUK;
    int b   = blockIdx.x % NBUK;
    int t   = threadIdx.x;
    const int* gchunk = dir ? gchunk1 : gchunk0;
    int* adj          = dir ? adj1 : adj0;
    int* offD         = dir ? off1 : off0;

    int len = 0, src = 0;
    if (t < NCH) {
        size_t idx = ((size_t)dir * NBUK + b) * NCH + t;
        len = ghist[idx];
        src = gstart[idx];
    }
    ssrc[t] = src;
    int tot;
    int ex = bscan256(len, s5, &tot);
    sdst[t] = ex;
    if (t == 0) sdst[256] = 0x7FFFFFFF;    // sentinel (unused)
    if (t < 64) fcnt[t] = 0;
    __syncthreads();
    int T = tot;

    // gather bucket pairs from chunk segments + fine histogram
    for (int i = t; i < T; i += 256) {
        int lo = 0, hi = 255;              // largest c with sdst[c] <= i
        while (lo < hi) {
            int mid = (lo + hi + 1) >> 1;
            if (sdst[mid] <= i) lo = mid; else hi = mid - 1;
        }
        int c = lo;
        int p = gchunk[(size_t)c * CHSZ + ssrc[c] + (i - sdst[c])];
        pairsS[i] = p;
        atomicAdd(&fcnt[p >> 16], 1);
    }
    __syncthreads();

    int bst = bstart[dir * NBUK + b];
    if (t < 64) {
        int x = fcnt[t];
        int y = wscan64(x, t);
        foff[t] = y - x;
        fcur[t] = y - x;
        int d = b * 64 + t;
        if (d < 50000) offD[d] = bst + foff[t];
    }
    __syncthreads();

    // scatter into block-exclusive adj region (L2 merges into full lines)
    for (int i = t; i < T; i += 256) {
        int p = pairsS[i];
        int slot = atomicAdd(&fcur[p >> 16], 1);
        adj[(size_t)bst + slot] = p & 0xFFFF;
    }
}

// ---------------- pass A: m[h] = B_inv[h] * sum_{v in h} x[v] --------------------
__global__ __launch_bounds__(256) void agg_a_k(const float* __restrict__ x,
                                               const int* __restrict__ adj,
                                               const int* __restrict__ off,
                                               float* __restrict__ m) {
    int h = blockIdx.x * 4 + (threadIdx.x >> 6);
    int l = threadIdx.x & 63;
    int s = off[h], e = off[h + 1];
    float ax = 0.f, ay = 0.f;
#pragma unroll 4
    for (int i = s; i < e; ++i) {
        int n = adj[i];
        float2 v = *(const float2*)(x + (size_t)n * 128 + 2 * l);
        ax += v.x; ay += v.y;
    }
    float inv = (e > s) ? 1.0f / (float)(e - s) : 0.0f;
    ((float2*)m)[(size_t)h * 64 + l] = make_float2(ax * inv, ay * inv);
}

// ---------------- pass B: out[v] = softmax(D_inv[v]*sum m[h] + b) ----------------
__global__ __launch_bounds__(256) void agg_b_k(const float* __restrict__ m,
                                               const int* __restrict__ adj,
                                               const int* __restrict__ off,
                                               const float* __restrict__ bias,
                                               float* __restrict__ out) {
    int v = blockIdx.x * 4 + (threadIdx.x >> 6);
    int l = threadIdx.x & 63;
    int s = off[v], e = off[v + 1];
    float ax = 0.f, ay = 0.f;
#pragma unroll 4
    for (int i = s; i < e; ++i) {
        int h = adj[i];
        float2 t = *(const float2*)(m + (size_t)h * 128 + 2 * l);
        ax += t.x; ay += t.y;
    }
    float inv = (e > s) ? 1.0f / (float)(e - s) : 0.0f;
    float2 bb = ((const float2*)bias)[l];
    float v0 = ax * inv + bb.x;
    float v1 = ay * inv + bb.y;

    float mx = fmaxf(v0, v1);
#pragma unroll
    for (int s2 = 32; s2 >= 1; s2 >>= 1) mx = fmaxf(mx, __shfl_xor(mx, s2, 64));
    float e0 = __expf(v0 - mx), e1 = __expf(v1 - mx);
    float sm = e0 + e1;
#pragma unroll
    for (int s2 = 32; s2 >= 1; s2 >>= 1) sm += __shfl_xor(sm, s2, 64);
    float r = 1.0f / sm;
    ((float2*)out)[(size_t)v * 64 + l] = make_float2(e0 * r, e1 * r);
}

// ---------------- launcher -------------------------------------------------------
extern "C" void kernel_launch(void* const* d_in, const int* in_sizes, int n_in,
                              void* d_out, int out_size, void* d_ws, size_t ws_size,
                              hipStream_t stream) {
    const float* X  = (const float*)d_in[0];
    const int*   ei = (const int*)d_in[1];
    const float* W  = (const float*)d_in[2];
    const float* b  = (const float*)d_in[3];
    float* out = (float*)d_out;

    int E = in_sizes[1] / 2;
    const int* nodes  = ei;
    const int* hedges = ei + E;
    int NCH = (E + CHSZ - 1) / CHSZ;       // 196 for E=1.6M (must be <= 256)

    // workspace layout (~67 MB)
    float* x = (float*)d_ws;                           // NN*F
    float* m = x + (size_t)NN * F;                     // NM*F
    int* gchunk0 = (int*)m;                            // NCH*CHSZ (aliased in m; consumed before m written)
    int* gchunk1 = gchunk0 + (size_t)NCH * CHSZ;       // NCH*CHSZ (12.85MB <= 25.6MB)
    int* adj0  = (int*)(m + (size_t)NM * F);           // E  (nodes grouped by hedge)
    int* adj1  = adj0 + E;                             // E  (hedges grouped by node)
    int* ghist = adj1 + E;                             // 2*NBUK*NCH
    int* gstart = ghist + 2 * (size_t)NBUK * NCH;      // 2*NBUK*NCH
    int* bstart = gstart + 2 * (size_t)NBUK * NCH;     // 2*NBUK
    int* off0 = bstart + 2 * NBUK;                     // 50001
    int* off1 = off0 + 50001;                          // 50001

    chunksort_k<<<2 * NCH, 256, 0, stream>>>(nodes, hedges, gchunk0, gchunk1, ghist, gstart, E, NCH);
    bucketbase_k<<<2, 1024, 0, stream>>>(ghist, bstart, off0, off1, E, NCH);
    merge_scatter_k<<<2 * NBUK, 256, 0, stream>>>(gchunk0, gchunk1, ghist, gstart, bstart,
                                                  adj0, adj1, off0, off1, NCH);
    gemm_k<<<NN / 16, 256, 0, stream>>>(X, W, x);
    agg_a_k<<<NM / 4, 256, 0, stream>>>(x, adj0, off0, m);
    agg_b_k<<<NN / 4, 256, 0, stream>>>(m, adj1, off1, b, out);
}

// Round 4
// 288.605 us; speedup vs baseline: 2.9228x; 1.2877x over previous
//
#include <hip/hip_runtime.h>
#include <hip/hip_fp16.h>

#define NN 50000
#define NM 50000
#define F  128
#define NBUK 782      // ceil(50000/64) buckets of 64 dest ids
#define CHSZ 8192     // edges per sort chunk

// ---------------- block-scan helpers ---------------------------------------------
__device__ __forceinline__ int wscan64(int v, int lane) {
    int x = v;
#pragma unroll
    for (int s = 1; s < 64; s <<= 1) {
        int u = __shfl_up(x, s, 64);
        if (lane >= s) x += u;
    }
    return x;   // inclusive
}

__device__ __forceinline__ int bscan256(int v, int* s5, int* tot) {
    int t = threadIdx.x, lane = t & 63, wid = t >> 6;
    int incl = wscan64(v, lane);
    if (lane == 63) s5[wid] = incl;
    __syncthreads();
    if (t == 0) {
        int a = 0;
#pragma unroll
        for (int j = 0; j < 4; ++j) { int x = s5[j]; s5[j] = a; a += x; }
        s5[4] = a;
    }
    __syncthreads();
    int ex = incl - v + s5[wid];
    *tot = s5[4];
    __syncthreads();
    return ex;
}

// ---------------- GEMM: x = X @ W -> fp16  ([NN,128] @ [128,128]) ----------------
__global__ __launch_bounds__(256) void gemm_k(const float* __restrict__ X,
                                              const float* __restrict__ W,
                                              __half* __restrict__ xo) {
    __shared__ float sW[128 * 128];
    __shared__ float sX[16 * 128];
    int t = threadIdx.x;

    const float4* W4 = (const float4*)W;
    float4* sW4 = (float4*)sW;
#pragma unroll
    for (int i = 0; i < 16; ++i) sW4[i * 256 + t] = W4[i * 256 + t];

    const float4* X4 = (const float4*)(X + (size_t)blockIdx.x * 16 * 128);
    float4* sX4 = (float4*)sX;
    sX4[t]       = X4[t];
    sX4[t + 256] = X4[t + 256];
    __syncthreads();

    int l = t & 63, w = t >> 6;           // lane owns cols 2l, 2l+1
    float acc[4][2] = {};
#pragma unroll 4
    for (int k = 0; k < 128; ++k) {
        float w0 = sW[k * 128 + 2 * l];
        float w1 = sW[k * 128 + 2 * l + 1];
#pragma unroll
        for (int r = 0; r < 4; ++r) {
            float xv = sX[(w * 4 + r) * 128 + k];
            acc[r][0] = fmaf(xv, w0, acc[r][0]);
            acc[r][1] = fmaf(xv, w1, acc[r][1]);
        }
    }
    int row0 = blockIdx.x * 16 + w * 4;
#pragma unroll
    for (int r = 0; r < 4; ++r)
        ((__half2*)xo)[(size_t)(row0 + r) * 64 + l] = __floats2half2_rn(acc[r][0], acc[r][1]);
}

// ---------------- 1: per-chunk LDS counting sort ---------------------------------
__global__ __launch_bounds__(256) void chunksort_k(const int* __restrict__ nodes,
                                                   const int* __restrict__ hedges,
                                                   int* __restrict__ gchunk0, int* __restrict__ gchunk1,
                                                   int* __restrict__ ghist, int* __restrict__ gstart,
                                                   int E, int NCH) {
    __shared__ int hist[NBUK];
    __shared__ int cursor[NBUK];
    __shared__ int pairs[CHSZ];
    __shared__ int s5[5];
    int dir = blockIdx.x / NCH;
    int c   = blockIdx.x % NCH;
    const int* key = dir ? nodes  : hedges;
    const int* pay = dir ? hedges : nodes;
    int* gchunk    = dir ? gchunk1 : gchunk0;
    int t = threadIdx.x;
    int e0 = c * CHSZ, e1 = min(E, e0 + CHSZ);

    for (int i = t; i < NBUK; i += 256) hist[i] = 0;
    __syncthreads();
    for (int e = e0 + t; e < e1; e += 256) atomicAdd(&hist[key[e] >> 6], 1);
    __syncthreads();

    int carry = 0;
    for (int base = 0; base < NBUK; base += 256) {
        int i = base + t;
        int v = (i < NBUK) ? hist[i] : 0;
        int tot;
        int ex = bscan256(v, s5, &tot);
        if (i < NBUK) cursor[i] = ex + carry;
        carry += tot;
    }
    __syncthreads();

    for (int b = t; b < NBUK; b += 256) {
        size_t idx = ((size_t)dir * NBUK + b) * NCH + c;
        ghist[idx]  = hist[b];
        gstart[idx] = cursor[b];
    }
    __syncthreads();

    for (int e = e0 + t; e < e1; e += 256) {
        int k = key[e];
        int pos = atomicAdd(&cursor[k >> 6], 1);
        pairs[pos] = ((k & 63) << 16) | pay[e];
    }
    __syncthreads();

    int n = e1 - e0;
    for (int i = t; i < n; i += 256) gchunk[(size_t)c * CHSZ + i] = pairs[i];
}

// ---------------- 2: bucket totals -> global bucket starts -----------------------
__global__ __launch_bounds__(1024) void bucketbase_k(const int* __restrict__ ghist,
                                                     int* __restrict__ bstart,
                                                     int* __restrict__ off0, int* __restrict__ off1,
                                                     int E, int NCH) {
    __shared__ int s16[17];
    int dir = blockIdx.x;
    int t = threadIdx.x, lane = t & 63, wid = t >> 6;
    int v = 0;
    if (t < NBUK) {
        const int* row = ghist + ((size_t)dir * NBUK + t) * NCH;
        int s = 0;
        for (int c = 0; c < NCH; ++c) s += row[c];
        v = s;
    }
    int incl = wscan64(v, lane);
    if (lane == 63) s16[wid] = incl;
    __syncthreads();
    if (t < 16) {
        int x = s16[t], y = x;
#pragma unroll
        for (int s = 1; s < 16; s <<= 1) {
            int u = __shfl_up(y, s, 64);
            if (t >= s) y += u;
        }
        s16[t] = y - x;
    }
    __syncthreads();
    int ex = incl - v + s16[wid];
    if (t < NBUK) bstart[dir * NBUK + t] = ex;
    if (t == 0) (dir ? off1 : off0)[50000] = E;
}

// ---------------- 3: per-bucket merge + fine sort + scatter ----------------------
__global__ __launch_bounds__(256) void merge_scatter_k(const int* __restrict__ gchunk0, const int* __restrict__ gchunk1,
                                                       const int* __restrict__ ghist, const int* __restrict__ gstart,
                                                       const int* __restrict__ bstart,
                                                       unsigned short* __restrict__ adj0, unsigned short* __restrict__ adj1,
                                                       int* __restrict__ off0, int* __restrict__ off1,
                                                       int NCH) {
    __shared__ int ssrc[256];
    __shared__ int sdst[257];
    __shared__ int s5[5];
    __shared__ int pairsS[CHSZ];
    __shared__ int fcnt[64], foff[64], fcur[64];

    int dir = blockIdx.x / NBUK;
    int b   = blockIdx.x % NBUK;
    int t   = threadIdx.x;
    const int* gchunk      = dir ? gchunk1 : gchunk0;
    unsigned short* adj    = dir ? adj1 : adj0;
    int* offD              = dir ? off1 : off0;

    int len = 0, src = 0;
    if (t < NCH) {
        size_t idx = ((size_t)dir * NBUK + b) * NCH + t;
        len = ghist[idx];
        src = gstart[idx];
    }
    ssrc[t] = src;
    int tot;
    int ex = bscan256(len, s5, &tot);
    sdst[t] = ex;
    if (t < 64) fcnt[t] = 0;
    __syncthreads();
    int T = tot;

    for (int i = t; i < T; i += 256) {
        int lo = 0, hi = 255;
        while (lo < hi) {
            int mid = (lo + hi + 1) >> 1;
            if (sdst[mid] <= i) lo = mid; else hi = mid - 1;
        }
        int c = lo;
        int p = gchunk[(size_t)c * CHSZ + ssrc[c] + (i - sdst[c])];
        pairsS[i] = p;
        atomicAdd(&fcnt[p >> 16], 1);
    }
    __syncthreads();

    int bst = bstart[dir * NBUK + b];
    if (t < 64) {
        int x = fcnt[t];
        int y = wscan64(x, t);
        foff[t] = y - x;
        fcur[t] = y - x;
        int d = b * 64 + t;
        if (d < 50000) offD[d] = bst + foff[t];
    }
    __syncthreads();

    for (int i = t; i < T; i += 256) {
        int p = pairsS[i];
        int slot = atomicAdd(&fcur[p >> 16], 1);
        adj[(size_t)bst + slot] = (unsigned short)(p & 0xFFFF);
    }
}

// ---------------- pass A: m[h] = B_inv[h] * sum_{v in h} x[v]  (fp16 tables) -----
__global__ __launch_bounds__(256) void agg_a_k(const __half2* __restrict__ x2,
                                               const unsigned short* __restrict__ adj,
                                               const int* __restrict__ off,
                                               __half2* __restrict__ m2) {
    int h = blockIdx.x * 4 + (threadIdx.x >> 6);
    int l = threadIdx.x & 63;
    int s = off[h], e = off[h + 1];
    float ax = 0.f, ay = 0.f;
#pragma unroll 4
    for (int i = s; i < e; ++i) {
        int n = adj[i];
        float2 v = __half22float2(x2[(size_t)n * 64 + l]);
        ax += v.x; ay += v.y;
    }
    float inv = (e > s) ? 1.0f / (float)(e - s) : 0.0f;
    m2[(size_t)h * 64 + l] = __floats2half2_rn(ax * inv, ay * inv);
}

// ---------------- pass B: out[v] = softmax(D_inv[v]*sum m[h] + b) ----------------
__global__ __launch_bounds__(256) void agg_b_k(const __half2* __restrict__ m2,
                                               const unsigned short* __restrict__ adj,
                                               const int* __restrict__ off,
                                               const float* __restrict__ bias,
                                               float* __restrict__ out) {
    int v = blockIdx.x * 4 + (threadIdx.x >> 6);
    int l = threadIdx.x & 63;
    int s = off[v], e = off[v + 1];
    float ax = 0.f, ay = 0.f;
#pragma unroll 4
    for (int i = s; i < e; ++i) {
        int h = adj[i];
        float2 t = __half22float2(m2[(size_t)h * 64 + l]);
        ax += t.x; ay += t.y;
    }
    float inv = (e > s) ? 1.0f / (float)(e - s) : 0.0f;
    float2 bb = ((const float2*)bias)[l];
    float v0 = ax * inv + bb.x;
    float v1 = ay * inv + bb.y;

    float mx = fmaxf(v0, v1);
#pragma unroll
    for (int s2 = 32; s2 >= 1; s2 >>= 1) mx = fmaxf(mx, __shfl_xor(mx, s2, 64));
    float e0 = __expf(v0 - mx), e1 = __expf(v1 - mx);
    float sm = e0 + e1;
#pragma unroll
    for (int s2 = 32; s2 >= 1; s2 >>= 1) sm += __shfl_xor(sm, s2, 64);
    float r = 1.0f / sm;
    ((float2*)out)[(size_t)v * 64 + l] = make_float2(e0 * r, e1 * r);
}

// ---------------- launcher -------------------------------------------------------
extern "C" void kernel_launch(void* const* d_in, const int* in_sizes, int n_in,
                              void* d_out, int out_size, void* d_ws, size_t ws_size,
                              hipStream_t stream) {
    const float* X  = (const float*)d_in[0];
    const int*   ei = (const int*)d_in[1];
    const float* W  = (const float*)d_in[2];
    const float* b  = (const float*)d_in[3];
    float* out = (float*)d_out;

    int E = in_sizes[1] / 2;
    const int* nodes  = ei;
    const int* hedges = ei + E;
    int NCH = (E + CHSZ - 1) / CHSZ;       // 196 for E=1.6M (must be <= 256)

    // workspace layout (~35 MB)
    __half* x = (__half*)d_ws;                          // NN*F fp16 (12.8 MB)
    __half* m = x + (size_t)NN * F;                     // NM*F fp16 (12.8 MB)
    // gchunk aliases the x+m region (consumed by merge_scatter BEFORE gemm/agg_a write x/m)
    int* gchunk0 = (int*)d_ws;                          // NCH*CHSZ ints
    int* gchunk1 = gchunk0 + (size_t)NCH * CHSZ;        // NCH*CHSZ ints (total 12.85 MB < 25.6 MB)
    unsigned short* adj0 = (unsigned short*)(m + (size_t)NM * F);   // E ushort
    unsigned short* adj1 = adj0 + E;                                // E ushort
    int* ghist  = (int*)(adj1 + E);                     // 2*NBUK*NCH
    int* gstart = ghist + 2 * (size_t)NBUK * NCH;       // 2*NBUK*NCH
    int* bstart = gstart + 2 * (size_t)NBUK * NCH;      // 2*NBUK
    int* off0 = bstart + 2 * NBUK;                      // 50001
    int* off1 = off0 + 50001;                           // 50001

    chunksort_k<<<2 * NCH, 256, 0, stream>>>(nodes, hedges, gchunk0, gchunk1, ghist, gstart, E, NCH);
    bucketbase_k<<<2, 1024, 0, stream>>>(ghist, bstart, off0, off1, E, NCH);
    merge_scatter_k<<<2 * NBUK, 256, 0, stream>>>(gchunk0, gchunk1, ghist, gstart, bstart,
                                                  adj0, adj1, off0, off1, NCH);
    gemm_k<<<NN / 16, 256, 0, stream>>>(X, W, x);
    agg_a_k<<<NM / 4, 256, 0, stream>>>((const __half2*)x, adj0, off0, (__half2*)m);
    agg_b_k<<<NN / 4, 256, 0, stream>>>((const __half2*)m, adj1, off1, b, out);
}

// Round 5
// 270.663 us; speedup vs baseline: 3.1165x; 1.0663x over previous
//
#include <hip/hip_runtime.h>
#include <hip/hip_fp16.h>

#define NN 50000
#define NM 50000
#define F  128
#define NBUK 782      // ceil(50000/64) buckets of 64 dest ids
#define CHSZ 8192     // edges per sort chunk
#define GEMM_BLKS (NN / 16)

// ---------------- block-scan helpers ---------------------------------------------
__device__ __forceinline__ int wscan64(int v, int lane) {
    int x = v;
#pragma unroll
    for (int s = 1; s < 64; s <<= 1) {
        int u = __shfl_up(x, s, 64);
        if (lane >= s) x += u;
    }
    return x;   // inclusive
}

__device__ __forceinline__ int bscan256(int v, int* s5, int* tot) {
    int t = threadIdx.x, lane = t & 63, wid = t >> 6;
    int incl = wscan64(v, lane);
    if (lane == 63) s5[wid] = incl;
    __syncthreads();
    if (t == 0) {
        int a = 0;
#pragma unroll
        for (int j = 0; j < 4; ++j) { int x = s5[j]; s5[j] = a; a += x; }
        s5[4] = a;
    }
    __syncthreads();
    int ex = incl - v + s5[wid];
    *tot = s5[4];
    __syncthreads();
    return ex;
}

// ---------------- fat kernel: chunksort blocks [0,nsort) + gemm blocks -----------
struct GemmSmem { float sW[128 * 128]; float sX[16 * 128]; };
struct SortSmem { int hist[NBUK]; int cursor[NBUK]; int pairs[CHSZ]; int s5[5]; };
union  FatSmem  { GemmSmem g; SortSmem s; };

__global__ __launch_bounds__(256) void fat_k(const float* __restrict__ X,
                                             const float* __restrict__ W,
                                             __half* __restrict__ xo,
                                             const int* __restrict__ nodes,
                                             const int* __restrict__ hedges,
                                             int* __restrict__ gchunk0, int* __restrict__ gchunk1,
                                             int* __restrict__ ghist, int* __restrict__ gstart,
                                             int E, int NCH, int nsort) {
    __shared__ FatSmem u;
    int t = threadIdx.x;

    if ((int)blockIdx.x < nsort) {
        // ---------------- chunksort ----------------
        int dir = blockIdx.x / NCH;
        int c   = blockIdx.x % NCH;
        const int* key = dir ? nodes  : hedges;
        const int* pay = dir ? hedges : nodes;
        int* gchunk    = dir ? gchunk1 : gchunk0;
        int e0 = c * CHSZ, e1 = min(E, e0 + CHSZ);

        for (int i = t; i < NBUK; i += 256) u.s.hist[i] = 0;
        __syncthreads();
        for (int e = e0 + t; e < e1; e += 256) atomicAdd(&u.s.hist[key[e] >> 6], 1);
        __syncthreads();

        int carry = 0;
        for (int base = 0; base < NBUK; base += 256) {
            int i = base + t;
            int v = (i < NBUK) ? u.s.hist[i] : 0;
            int tot;
            int ex = bscan256(v, u.s.s5, &tot);
            if (i < NBUK) u.s.cursor[i] = ex + carry;
            carry += tot;
        }
        __syncthreads();

        for (int b = t; b < NBUK; b += 256) {
            size_t idx = ((size_t)dir * NBUK + b) * NCH + c;
            ghist[idx]  = u.s.hist[b];
            gstart[idx] = u.s.cursor[b];
        }
        __syncthreads();

        for (int e = e0 + t; e < e1; e += 256) {
            int k = key[e];
            int pos = atomicAdd(&u.s.cursor[k >> 6], 1);
            u.s.pairs[pos] = ((k & 63) << 16) | pay[e];
        }
        __syncthreads();

        int n = e1 - e0;
        for (int i = t; i < n; i += 256) gchunk[(size_t)c * CHSZ + i] = u.s.pairs[i];
    } else {
        // ---------------- gemm: x = X @ W -> fp16 ----------------
        int gb = blockIdx.x - nsort;

        const float4* W4 = (const float4*)W;
        float4* sW4 = (float4*)u.g.sW;
#pragma unroll
        for (int i = 0; i < 16; ++i) sW4[i * 256 + t] = W4[i * 256 + t];

        const float4* X4 = (const float4*)(X + (size_t)gb * 16 * 128);
        float4* sX4 = (float4*)u.g.sX;
        sX4[t]       = X4[t];
        sX4[t + 256] = X4[t + 256];
        __syncthreads();

        int l = t & 63, w = t >> 6;
        float acc[4][2] = {};
#pragma unroll 4
        for (int k = 0; k < 128; ++k) {
            float w0 = u.g.sW[k * 128 + 2 * l];
            float w1 = u.g.sW[k * 128 + 2 * l + 1];
#pragma unroll
            for (int r = 0; r < 4; ++r) {
                float xv = u.g.sX[(w * 4 + r) * 128 + k];
                acc[r][0] = fmaf(xv, w0, acc[r][0]);
                acc[r][1] = fmaf(xv, w1, acc[r][1]);
            }
        }
        int row0 = gb * 16 + w * 4;
#pragma unroll
        for (int r = 0; r < 4; ++r)
            ((__half2*)xo)[(size_t)(row0 + r) * 64 + l] = __floats2half2_rn(acc[r][0], acc[r][1]);
    }
}

// ---------------- 2: bucket totals -> global bucket starts -----------------------
__global__ __launch_bounds__(1024) void bucketbase_k(const int* __restrict__ ghist,
                                                     int* __restrict__ bstart,
                                                     int* __restrict__ off0, int* __restrict__ off1,
                                                     int E, int NCH) {
    __shared__ int s16[17];
    int dir = blockIdx.x;
    int t = threadIdx.x, lane = t & 63, wid = t >> 6;
    int v = 0;
    if (t < NBUK) {
        const int* row = ghist + ((size_t)dir * NBUK + t) * NCH;
        int s = 0;
#pragma unroll 4
        for (int c = 0; c < NCH; ++c) s += row[c];
        v = s;
    }
    int incl = wscan64(v, lane);
    if (lane == 63) s16[wid] = incl;
    __syncthreads();
    if (t < 16) {
        int x = s16[t], y = x;
#pragma unroll
        for (int s = 1; s < 16; s <<= 1) {
            int u = __shfl_up(y, s, 64);
            if (t >= s) y += u;
        }
        s16[t] = y - x;
    }
    __syncthreads();
    int ex = incl - v + s16[wid];
    if (t < NBUK) bstart[dir * NBUK + t] = ex;
    if (t == 0) (dir ? off1 : off0)[50000] = E;
}

// ---------------- 3: per-bucket merge + fine sort + scatter ----------------------
__global__ __launch_bounds__(256) void merge_scatter_k(const int* __restrict__ gchunk0, const int* __restrict__ gchunk1,
                                                       const int* __restrict__ ghist, const int* __restrict__ gstart,
                                                       const int* __restrict__ bstart,
                                                       unsigned short* __restrict__ adj0, unsigned short* __restrict__ adj1,
                                                       int* __restrict__ off0, int* __restrict__ off1,
                                                       int NCH) {
    __shared__ int ssrc[256];
    __shared__ int sdst[257];
    __shared__ int s5[5];
    __shared__ int pairsS[CHSZ];
    __shared__ int fcnt[64], foff[64], fcur[64];

    int dir = blockIdx.x / NBUK;
    int b   = blockIdx.x % NBUK;
    int t   = threadIdx.x;
    const int* gchunk      = dir ? gchunk1 : gchunk0;
    unsigned short* adj    = dir ? adj1 : adj0;
    int* offD              = dir ? off1 : off0;

    int len = 0, src = 0;
    if (t < NCH) {
        size_t idx = ((size_t)dir * NBUK + b) * NCH + t;
        len = ghist[idx];
        src = gstart[idx];
    }
    ssrc[t] = src;
    int tot;
    int ex = bscan256(len, s5, &tot);
    sdst[t] = ex;
    if (t == 0) sdst[256] = 0x7FFFFFFF;
    if (t < 64) fcnt[t] = 0;
    __syncthreads();
    int T = tot;

    // contiguous per-thread range: one binary search + monotone walk
    int per = (T + 255) >> 8;
    int i0 = t * per, i1 = min(T, i0 + per);
    if (i0 < i1) {
        int lo = 0, hi = 255;
        while (lo < hi) {
            int mid = (lo + hi + 1) >> 1;
            if (sdst[mid] <= i0) lo = mid; else hi = mid - 1;
        }
        int c = lo;
        for (int i = i0; i < i1; ++i) {
            while (c < 255 && sdst[c + 1] <= i) ++c;
            int p = gchunk[(size_t)c * CHSZ + ssrc[c] + (i - sdst[c])];
            pairsS[i] = p;
            atomicAdd(&fcnt[p >> 16], 1);
        }
    }
    __syncthreads();

    int bst = bstart[dir * NBUK + b];
    if (t < 64) {
        int x = fcnt[t];
        int y = wscan64(x, t);
        foff[t] = y - x;
        fcur[t] = y - x;
        int d = b * 64 + t;
        if (d < 50000) offD[d] = bst + foff[t];
    }
    __syncthreads();

    for (int i = t; i < T; i += 256) {
        int p = pairsS[i];
        int slot = atomicAdd(&fcur[p >> 16], 1);
        adj[(size_t)bst + slot] = (unsigned short)(p & 0xFFFF);
    }
}

// ---------------- pass A: m[h] = B_inv[h] * sum_{v in h} x[v]  (fp16 tables) -----
__global__ __launch_bounds__(256) void agg_a_k(const __half2* __restrict__ x2,
                                               const unsigned short* __restrict__ adj,
                                               const int* __restrict__ off,
                                               __half2* __restrict__ m2) {
    int h = blockIdx.x * 4 + (threadIdx.x >> 6);
    int l = threadIdx.x & 63;
    int s = off[h], e = off[h + 1];
    float a0x = 0.f, a0y = 0.f, a1x = 0.f, a1y = 0.f;
    float a2x = 0.f, a2y = 0.f, a3x = 0.f, a3y = 0.f;
    int i = s;
    for (; i + 8 <= e; i += 8) {
        int n0 = adj[i], n1 = adj[i + 1], n2 = adj[i + 2], n3 = adj[i + 3];
        int n4 = adj[i + 4], n5 = adj[i + 5], n6 = adj[i + 6], n7 = adj[i + 7];
        float2 v0 = __half22float2(x2[(size_t)n0 * 64 + l]);
        float2 v1 = __half22float2(x2[(size_t)n1 * 64 + l]);
        float2 v2 = __half22float2(x2[(size_t)n2 * 64 + l]);
        float2 v3 = __half22float2(x2[(size_t)n3 * 64 + l]);
        float2 v4 = __half22float2(x2[(size_t)n4 * 64 + l]);
        float2 v5 = __half22float2(x2[(size_t)n5 * 64 + l]);
        float2 v6 = __half22float2(x2[(size_t)n6 * 64 + l]);
        float2 v7 = __half22float2(x2[(size_t)n7 * 64 + l]);
        a0x += v0.x; a0y += v0.y; a1x += v1.x; a1y += v1.y;
        a2x += v2.x; a2y += v2.y; a3x += v3.x; a3y += v3.y;
        a0x += v4.x; a0y += v4.y; a1x += v5.x; a1y += v5.y;
        a2x += v6.x; a2y += v6.y; a3x += v7.x; a3y += v7.y;
    }
    for (; i < e; ++i) {
        float2 v = __half22float2(x2[(size_t)adj[i] * 64 + l]);
        a0x += v.x; a0y += v.y;
    }
    float ax = (a0x + a1x) + (a2x + a3x);
    float ay = (a0y + a1y) + (a2y + a3y);
    float inv = (e > s) ? 1.0f / (float)(e - s) : 0.0f;
    m2[(size_t)h * 64 + l] = __floats2half2_rn(ax * inv, ay * inv);
}

// ---------------- pass B: out[v] = softmax(D_inv[v]*sum m[h] + b) ----------------
__global__ __launch_bounds__(256) void agg_b_k(const __half2* __restrict__ m2,
                                               const unsigned short* __restrict__ adj,
                                               const int* __restrict__ off,
                                               const float* __restrict__ bias,
                                               float* __restrict__ out) {
    int v = blockIdx.x * 4 + (threadIdx.x >> 6);
    int l = threadIdx.x & 63;
    int s = off[v], e = off[v + 1];
    float a0x = 0.f, a0y = 0.f, a1x = 0.f, a1y = 0.f;
    float a2x = 0.f, a2y = 0.f, a3x = 0.f, a3y = 0.f;
    int i = s;
    for (; i + 8 <= e; i += 8) {
        int n0 = adj[i], n1 = adj[i + 1], n2 = adj[i + 2], n3 = adj[i + 3];
        int n4 = adj[i + 4], n5 = adj[i + 5], n6 = adj[i + 6], n7 = adj[i + 7];
        float2 v0 = __half22float2(m2[(size_t)n0 * 64 + l]);
        float2 v1 = __half22float2(m2[(size_t)n1 * 64 + l]);
        float2 v2 = __half22float2(m2[(size_t)n2 * 64 + l]);
        float2 v3 = __half22float2(m2[(size_t)n3 * 64 + l]);
        float2 v4 = __half22float2(m2[(size_t)n4 * 64 + l]);
        float2 v5 = __half22float2(m2[(size_t)n5 * 64 + l]);
        float2 v6 = __half22float2(m2[(size_t)n6 * 64 + l]);
        float2 v7 = __half22float2(m2[(size_t)n7 * 64 + l]);
        a0x += v0.x; a0y += v0.y; a1x += v1.x; a1y += v1.y;
        a2x += v2.x; a2y += v2.y; a3x += v3.x; a3y += v3.y;
        a0x += v4.x; a0y += v4.y; a1x += v5.x; a1y += v5.y;
        a2x += v6.x; a2y += v6.y; a3x += v7.x; a3y += v7.y;
    }
    for (; i < e; ++i) {
        float2 t2 = __half22float2(m2[(size_t)adj[i] * 64 + l]);
        a0x += t2.x; a0y += t2.y;
    }
    float ax = (a0x + a1x) + (a2x + a3x);
    float ay = (a0y + a1y) + (a2y + a3y);
    float inv = (e > s) ? 1.0f / (float)(e - s) : 0.0f;
    float2 bb = ((const float2*)bias)[l];
    float v0 = ax * inv + bb.x;
    float v1 = ay * inv + bb.y;

    float mx = fmaxf(v0, v1);
#pragma unroll
    for (int s2 = 32; s2 >= 1; s2 >>= 1) mx = fmaxf(mx, __shfl_xor(mx, s2, 64));
    float e0 = __expf(v0 - mx), e1 = __expf(v1 - mx);
    float sm = e0 + e1;
#pragma unroll
    for (int s2 = 32; s2 >= 1; s2 >>= 1) sm += __shfl_xor(sm, s2, 64);
    float r = 1.0f / sm;
    ((float2*)out)[(size_t)v * 64 + l] = make_float2(e0 * r, e1 * r);
}

// ---------------- launcher -------------------------------------------------------
extern "C" void kernel_launch(void* const* d_in, const int* in_sizes, int n_in,
                              void* d_out, int out_size, void* d_ws, size_t ws_size,
                              hipStream_t stream) {
    const float* X  = (const float*)d_in[0];
    const int*   ei = (const int*)d_in[1];
    const float* W  = (const float*)d_in[2];
    const float* b  = (const float*)d_in[3];
    float* out = (float*)d_out;

    int E = in_sizes[1] / 2;
    const int* nodes  = ei;
    const int* hedges = ei + E;
    int NCH = (E + CHSZ - 1) / CHSZ;       // 196 for E=1.6M (must be <= 256)
    int nsort = 2 * NCH;

    // workspace layout (~48 MB) — gchunk no longer aliases x (fat kernel runs both concurrently)
    __half* x = (__half*)d_ws;                          // NN*F fp16 (12.8 MB)
    __half* m = x + (size_t)NN * F;                     // NM*F fp16 (12.8 MB)
    int* gchunk0 = (int*)(m + (size_t)NM * F);          // NCH*CHSZ ints
    int* gchunk1 = gchunk0 + (size_t)NCH * CHSZ;        // NCH*CHSZ ints
    unsigned short* adj0 = (unsigned short*)(gchunk1 + (size_t)NCH * CHSZ);  // E ushort
    unsigned short* adj1 = adj0 + E;                                         // E ushort
    int* ghist  = (int*)(adj1 + E);                     // 2*NBUK*NCH
    int* gstart = ghist + 2 * (size_t)NBUK * NCH;       // 2*NBUK*NCH
    int* bstart = gstart + 2 * (size_t)NBUK * NCH;      // 2*NBUK
    int* off0 = bstart + 2 * NBUK;                      // 50001
    int* off1 = off0 + 50001;                           // 50001

    fat_k<<<nsort + GEMM_BLKS, 256, 0, stream>>>(X, W, x, nodes, hedges,
                                                 gchunk0, gchunk1, ghist, gstart, E, NCH, nsort);
    bucketbase_k<<<2, 1024, 0, stream>>>(ghist, bstart, off0, off1, E, NCH);
    merge_scatter_k<<<2 * NBUK, 256, 0, stream>>>(gchunk0, gchunk1, ghist, gstart, bstart,
                                                  adj0, adj1, off0, off1, NCH);
    agg_a_k<<<NM / 4, 256, 0, stream>>>((const __half2*)x, adj0, off0, (__half2*)m);
    agg_b_k<<<NN / 4, 256, 0, stream>>>((const __half2*)m, adj1, off1, b, out);
}